// Round 3
// baseline (751.322 us; speedup 1.0000x reference)
//
#include <hip/hip_runtime.h>
#include <hip/hip_bf16.h>
#include <stdint.h>

typedef uint32_t u32;
typedef uint16_t u16;
typedef __attribute__((ext_vector_type(8))) short short8;
typedef __attribute__((ext_vector_type(4))) float floatx4;

#define NH 16
#define HD 128
#define TSEQ 2048
#define NB 4
#define CM 2048
#define MROWS (NB*TSEQ)      // 8192
#define NQKV (3*CM)          // 6144

__device__ __forceinline__ u16 f2bf(float f) {
    union { float f; u32 u; } v; v.f = f;
    return (u16)((v.u + 0x7fffu + ((v.u >> 16) & 1u)) >> 16);
}

// ---------------- conversion kernels ----------------
__global__ __launch_bounds__(256) void convert_x_kernel(const float* __restrict__ in,
                                                        u16* __restrict__ out) {
    int idx = (blockIdx.x * 256 + threadIdx.x) * 8;
    float4 a = *(const float4*)(in + idx);
    float4 b = *(const float4*)(in + idx + 4);
    union { u16 s[8]; uint4 v; } o;
    o.s[0] = f2bf(a.x); o.s[1] = f2bf(a.y); o.s[2] = f2bf(a.z); o.s[3] = f2bf(a.w);
    o.s[4] = f2bf(b.x); o.s[5] = f2bf(b.y); o.s[6] = f2bf(b.z); o.s[7] = f2bf(b.w);
    *(uint4*)(out + idx) = o.v;
}

// in: [R][Cn] fp32 row-major  ->  out: [Cn][R] bf16 row-major
__global__ __launch_bounds__(256) void transpose_bf_kernel(const float* __restrict__ in,
                                                           u16* __restrict__ out,
                                                           int R, int Cn) {
    __shared__ float tile[32][33];
    int tx = threadIdx.x, ty = threadIdx.y;
    int c0 = blockIdx.x * 32, r0 = blockIdx.y * 32;
#pragma unroll
    for (int i = 0; i < 4; i++)
        tile[ty + i * 8][tx] = in[(size_t)(r0 + ty + i * 8) * Cn + c0 + tx];
    __syncthreads();
#pragma unroll
    for (int i = 0; i < 4; i++)
        out[(size_t)(c0 + ty + i * 8) * R + r0 + tx] = f2bf(tile[tx][ty + i * 8]);
}

// ---------------- QKV GEMM with fused RoPE + scatter ----------------
// Prefetch issued AFTER the second barrier: its latency hides under the MFMA
// phase and is drained at the NEXT iteration's first barrier (hipcc emits
// vmcnt(0) before s_barrier, so issuing between the barriers exposes it).
__global__ __launch_bounds__(256, 2) void gemm_qkv_rope(const u16* __restrict__ A,
                                                        const u16* __restrict__ BT,
                                                        const float* __restrict__ sinp,
                                                        const float* __restrict__ cosp,
                                                        u16* __restrict__ q_ws,
                                                        u16* __restrict__ k_ws,
                                                        u16* __restrict__ v_ws) {
    __shared__ u16 As[128 * 40];
    __shared__ u16 Bs[128 * 40];
    int tid = threadIdx.x;
    int w = tid >> 6, lane = tid & 63, quad = lane >> 4, l15 = lane & 15;
    int mw = (w >> 1) * 64, nw = (w & 1) * 64;
    int blk = blockIdx.x;
    int xcd = blk & 7, idx8 = blk >> 3;           // idx8: 0..383
    int rowBase = (xcd * 8 + (idx8 & 7)) * 128;   // row tile 0..63
    int colBase = (idx8 >> 3) * 128;              // col tile 0..47

    floatx4 acc[4][4];
#pragma unroll
    for (int mi = 0; mi < 4; mi++)
#pragma unroll
        for (int ni = 0; ni < 4; ni++) acc[mi][ni] = (floatx4){0.f, 0.f, 0.f, 0.f};

    int r0s = tid >> 2, c8s = (tid & 3) * 8;      // p=0 slice
    int r1s = (tid + 256) >> 2;                   // p=1 slice (same c8s)
    const u16* Arow0 = A + (size_t)(rowBase + r0s) * CM + c8s;
    const u16* Arow1 = A + (size_t)(rowBase + r1s) * CM + c8s;
    const u16* Brow0 = BT + (size_t)(colBase + r0s) * CM + c8s;
    const u16* Brow1 = BT + (size_t)(colBase + r1s) * CM + c8s;

    uint4 pa0 = *(const uint4*)(Arow0), pa1 = *(const uint4*)(Arow1);
    uint4 pb0 = *(const uint4*)(Brow0), pb1 = *(const uint4*)(Brow1);

    for (int k0 = 0; k0 < CM; k0 += 32) {
        __syncthreads();
        *(uint4*)(&As[r0s * 40 + c8s]) = pa0;
        *(uint4*)(&As[r1s * 40 + c8s]) = pa1;
        *(uint4*)(&Bs[r0s * 40 + c8s]) = pb0;
        *(uint4*)(&Bs[r1s * 40 + c8s]) = pb1;
        __syncthreads();
        if (k0 + 32 < CM) {   // prefetch next K-slab; latency overlaps MFMAs below
            pa0 = *(const uint4*)(Arow0 + k0 + 32);
            pa1 = *(const uint4*)(Arow1 + k0 + 32);
            pb0 = *(const uint4*)(Brow0 + k0 + 32);
            pb1 = *(const uint4*)(Brow1 + k0 + 32);
        }
        short8 af[4], bf[4];
#pragma unroll
        for (int mi = 0; mi < 4; mi++)
            af[mi] = *(const short8*)(&As[(mw + mi * 16 + l15) * 40 + quad * 8]);
#pragma unroll
        for (int ni = 0; ni < 4; ni++)
            bf[ni] = *(const short8*)(&Bs[(nw + ni * 16 + l15) * 40 + quad * 8]);
#pragma unroll
        for (int mi = 0; mi < 4; mi++)
#pragma unroll
            for (int ni = 0; ni < 4; ni++)
                acc[mi][ni] = __builtin_amdgcn_mfma_f32_16x16x32_bf16(af[mi], bf[ni],
                                                                      acc[mi][ni], 0, 0, 0);
    }

    const float inv_sqrt_hd = 0.08838834764831845f;
#pragma unroll
    for (int mi = 0; mi < 4; mi++) {
#pragma unroll
        for (int ni = 0; ni < 4; ni++) {
            int j = colBase + nw + ni * 16 + l15;
            int sec = j >> 11;
            int jj = j & 2047;
            int h = jj >> 7, d = jj & 127;
            if (sec == 2) {
                // V: pack 4 consecutive-t bf16, transposed layout [b][h][d][t]
                int r0 = rowBase + mw + mi * 16 + quad * 4;
                int b = r0 >> 11, t0 = r0 & 2047;
                union { u16 s[4]; uint2 v; } pk;
#pragma unroll
                for (int reg = 0; reg < 4; reg++) pk.s[reg] = f2bf(acc[mi][ni][reg]);
                *(uint2*)(&v_ws[((size_t)(b * NH + h) * HD + d) * TSEQ + t0]) = pk.v;
            } else {
#pragma unroll
                for (int reg = 0; reg < 4; reg++) {
                    int r = rowBase + mw + mi * 16 + quad * 4 + reg;
                    int b = r >> 11, t = r & 2047;
                    float v = acc[mi][ni][reg];
                    float partner = __shfl_xor(v, 1, 64);
                    size_t dsti = (size_t)((b * NH + h) * TSEQ + t) * HD + d;
                    float s = sinp[t * HD + d], c = cosp[t * HD + d];
                    float o = v * c + ((d & 1) ? partner * s : -partner * s);
                    if (sec == 0) o *= inv_sqrt_hd;
                    ((sec == 0) ? q_ws : k_ws)[dsti] = f2bf(o);
                }
            }
        }
    }
}

// ---------------- flash attention (causal, no-max softmax) ----------------
// Staging loads fully coalesced; LDS XOR-swizzled (conflict-free both sides);
// prefetch after second barrier (overlaps compute, drains at next top barrier).
// __launch_bounds__(256,1): cap 512 regs. Spill ladder evidence:
//   (256,3) cap~170: VGPR 84,  WRITE 799MB, 411us
//   (256,2) cap 256: VGPR 120, WRITE 453MB, 291us   <- still ~420MB scratch r/w per run
// Live set is ~200+ regs (O 64 + qf 32 + kreg/vreg 32 + transients); give the
// allocator room. HW occupancy follows ACTUAL alloc (<=256 -> 2 blocks/CU).
// LDS: smem 32KB = Q stage, then Ks [16][64][8] + Vt [8][128][8]; Ps [128][72]
__global__ __launch_bounds__(256, 1) void attn_kernel(const u16* __restrict__ q_ws,
                                                      const u16* __restrict__ k_ws,
                                                      const u16* __restrict__ vt_ws,
                                                      u16* __restrict__ y_bf) {
    __shared__ u16 smem[16 * 1024];   // 32 KB
    __shared__ u16 Ps[128 * 72];      // 18.4 KB
    u16* Ks = smem;                   // [s=0..15][key^s7][8]
    u16* Vt = smem + 8192;            // [s=0..7][d^s][8]
    int tid = threadIdx.x;
    int w = tid >> 6, lane = tid & 63, quad = lane >> 4, l15 = lane & 15;
    int qt = 15 - (blockIdx.x >> 6);   // qt slow index: big tiles dispatch first
    int bh = blockIdx.x & 63;
    int b = bh >> 4, h = bh & 15;
    const u16* Qg = q_ws + (size_t)bh * TSEQ * HD;
    const u16* Kg = k_ws + (size_t)bh * TSEQ * HD;
    const u16* Vg = vt_ws + (size_t)bh * HD * TSEQ;

    // issue tile-0 K/V loads first (latency hides under Q staging below)
    uint4 kreg[4], vreg[4];
#pragma unroll
    for (int j = 0; j < 4; j++) {
        int idx = j * 256 + tid;
        int key = idx >> 4, s = idx & 15;
        kreg[j] = *(const uint4*)(Kg + (size_t)key * HD + s * 8);
    }
#pragma unroll
    for (int j = 0; j < 4; j++) {
        int idx = j * 256 + tid;
        int d = idx >> 3, s = idx & 7;
        vreg[j] = *(const uint4*)(Vg + (size_t)d * TSEQ + s * 8);
    }

    // stage Q tile (128x128) through smem, coalesced, then read fragments
#pragma unroll
    for (int j = 0; j < 8; j++) {
        int idx = j * 256 + tid;
        int row = idx >> 4, s = idx & 15;
        uint4 qv = *(const uint4*)(Qg + (size_t)(qt * 128 + row) * HD + s * 8);
        *(uint4*)(&smem[s * 1024 + ((row ^ (s & 7)) * 8)]) = qv;
    }
    __syncthreads();
    short8 qf[2][4];
#pragma unroll
    for (int mi = 0; mi < 2; mi++)
#pragma unroll
        for (int kk = 0; kk < 4; kk++) {
            int row = w * 32 + mi * 16 + l15;
            int s = kk * 4 + quad;
            qf[mi][kk] = *(const short8*)(&smem[s * 1024 + ((row ^ (s & 7)) * 8)]);
        }
    // loop-top barrier protects smem reuse (Q -> Ks/Vt)

    floatx4 O[2][8];
#pragma unroll
    for (int mi = 0; mi < 2; mi++)
#pragma unroll
        for (int f = 0; f < 8; f++) O[mi][f] = (floatx4){0.f, 0.f, 0.f, 0.f};
    float l_i[2][4];
#pragma unroll
    for (int mi = 0; mi < 2; mi++)
#pragma unroll
        for (int g = 0; g < 4; g++) l_i[mi][g] = 0.f;

    int ktmax = 2 * qt + 1;
    for (int kt = 0; kt <= ktmax; kt++) {
        __syncthreads();
#pragma unroll
        for (int j = 0; j < 4; j++) {
            int idx = j * 256 + tid;
            int key = idx >> 4, s = idx & 15;
            *(uint4*)(&Ks[s * 512 + ((key ^ (s & 7)) * 8)]) = kreg[j];
        }
#pragma unroll
        for (int j = 0; j < 4; j++) {
            int idx = j * 256 + tid;
            int d = idx >> 3, s = idx & 7;
            *(uint4*)(&Vt[s * 1024 + ((d ^ s) * 8)]) = vreg[j];
        }
        __syncthreads();
        if (kt < ktmax) {   // prefetch next tile; overlaps compute below
            const u16* Ktg = Kg + (size_t)((kt + 1) * 64) * HD;
            const u16* Vtg = Vg + (kt + 1) * 64;
#pragma unroll
            for (int j = 0; j < 4; j++) {
                int idx = j * 256 + tid;
                int key = idx >> 4, s = idx & 15;
                kreg[j] = *(const uint4*)(Ktg + (size_t)key * HD + s * 8);
            }
#pragma unroll
            for (int j = 0; j < 4; j++) {
                int idx = j * 256 + tid;
                int d = idx >> 3, s = idx & 7;
                vreg[j] = *(const uint4*)(Vtg + (size_t)d * TSEQ + s * 8);
            }
        }

        // S = Q K^T : rows = this wave's 32 queries, cols = 64 keys
        floatx4 S[2][4];
#pragma unroll
        for (int nf = 0; nf < 4; nf++) {
            short8 bb[4];
#pragma unroll
            for (int kk = 0; kk < 4; kk++) {
                int s = kk * 4 + quad;
                int key = nf * 16 + l15;
                bb[kk] = *(const short8*)(&Ks[s * 512 + ((key ^ (s & 7)) * 8)]);
            }
#pragma unroll
            for (int mi = 0; mi < 2; mi++) {
                floatx4 a4 = (floatx4){0.f, 0.f, 0.f, 0.f};
#pragma unroll
                for (int kk = 0; kk < 4; kk++)
                    a4 = __builtin_amdgcn_mfma_f32_16x16x32_bf16(qf[mi][kk], bb[kk], a4, 0, 0, 0);
                S[mi][nf] = a4;
            }
        }
        if (kt >= 2 * qt) {   // diagonal region: mask key > query (exp(-1e4) == 0)
#pragma unroll
            for (int mi = 0; mi < 2; mi++)
#pragma unroll
                for (int nf = 0; nf < 4; nf++) {
                    int key = kt * 64 + nf * 16 + l15;
#pragma unroll
                    for (int reg = 0; reg < 4; reg++) {
                        int query = qt * 128 + w * 32 + mi * 16 + quad * 4 + reg;
                        if (key > query) S[mi][nf][reg] = -1e4f;
                    }
                }
        }
        // p = exp(S); accumulate per-lane l; stage P for the PV MFMA
#pragma unroll
        for (int mi = 0; mi < 2; mi++)
#pragma unroll
            for (int nf = 0; nf < 4; nf++)
#pragma unroll
                for (int reg = 0; reg < 4; reg++) {
                    float p = __expf(S[mi][nf][reg]);
                    l_i[mi][reg] += p;
                    Ps[(w * 32 + mi * 16 + quad * 4 + reg) * 72 + nf * 16 + l15] = f2bf(p);
                }
        // O += P V  (Ps rows produced & consumed by same wave; no barrier needed)
        short8 pa[2][2];
#pragma unroll
        for (int mi = 0; mi < 2; mi++)
#pragma unroll
            for (int kk = 0; kk < 2; kk++)
                pa[mi][kk] = *(const short8*)(&Ps[(w * 32 + mi * 16 + l15) * 72 +
                                                  kk * 32 + quad * 8]);
#pragma unroll
        for (int f = 0; f < 8; f++) {
            short8 vb[2];
#pragma unroll
            for (int kk = 0; kk < 2; kk++) {
                int s = kk * 4 + quad;
                int d = f * 16 + l15;
                vb[kk] = *(const short8*)(&Vt[s * 1024 + ((d ^ s) * 8)]);
            }
#pragma unroll
            for (int mi = 0; mi < 2; mi++)
#pragma unroll
                for (int kk = 0; kk < 2; kk++)
                    O[mi][f] = __builtin_amdgcn_mfma_f32_16x16x32_bf16(pa[mi][kk], vb[kk],
                                                                       O[mi][f], 0, 0, 0);
        }
    }

    float inv[2][4];
#pragma unroll
    for (int mi = 0; mi < 2; mi++)
#pragma unroll
        for (int reg = 0; reg < 4; reg++) {
            float l = l_i[mi][reg];
#pragma unroll
            for (int off = 1; off < 16; off <<= 1) l += __shfl_xor(l, off, 64);
            inv[mi][reg] = 1.0f / l;
        }
#pragma unroll
    for (int mi = 0; mi < 2; mi++)
#pragma unroll
        for (int f = 0; f < 8; f++)
#pragma unroll
            for (int reg = 0; reg < 4; reg++) {
                int t = qt * 128 + w * 32 + mi * 16 + quad * 4 + reg;
                int col = h * HD + f * 16 + l15;
                y_bf[(size_t)(b * TSEQ + t) * CM + col] = f2bf(O[mi][f][reg] * inv[mi][reg]);
            }
}

// ---------------- projection GEMM ----------------
__global__ __launch_bounds__(256, 2) void gemm_proj(const u16* __restrict__ A,
                                                    const u16* __restrict__ BT,
                                                    float* __restrict__ out) {
    __shared__ u16 As[128 * 40];
    __shared__ u16 Bs[128 * 40];
    int tid = threadIdx.x;
    int w = tid >> 6, lane = tid & 63, quad = lane >> 4, l15 = lane & 15;
    int mw = (w >> 1) * 64, nw = (w & 1) * 64;
    int blk = blockIdx.x;
    int xcd = blk & 7, idx8 = blk >> 3;           // idx8: 0..127
    int rowBase = (xcd * 8 + (idx8 & 7)) * 128;   // row tile 0..63
    int colBase = (idx8 >> 3) * 128;              // col tile 0..15

    floatx4 acc[4][4];
#pragma unroll
    for (int mi = 0; mi < 4; mi++)
#pragma unroll
        for (int ni = 0; ni < 4; ni++) acc[mi][ni] = (floatx4){0.f, 0.f, 0.f, 0.f};

    int r0s = tid >> 2, c8s = (tid & 3) * 8;
    int r1s = (tid + 256) >> 2;
    const u16* Arow0 = A + (size_t)(rowBase + r0s) * CM + c8s;
    const u16* Arow1 = A + (size_t)(rowBase + r1s) * CM + c8s;
    const u16* Brow0 = BT + (size_t)(colBase + r0s) * CM + c8s;
    const u16* Brow1 = BT + (size_t)(colBase + r1s) * CM + c8s;

    uint4 pa0 = *(const uint4*)(Arow0), pa1 = *(const uint4*)(Arow1);
    uint4 pb0 = *(const uint4*)(Brow0), pb1 = *(const uint4*)(Brow1);

    for (int k0 = 0; k0 < CM; k0 += 32) {
        __syncthreads();
        *(uint4*)(&As[r0s * 40 + c8s]) = pa0;
        *(uint4*)(&As[r1s * 40 + c8s]) = pa1;
        *(uint4*)(&Bs[r0s * 40 + c8s]) = pb0;
        *(uint4*)(&Bs[r1s * 40 + c8s]) = pb1;
        __syncthreads();
        if (k0 + 32 < CM) {   // prefetch next K-slab; latency overlaps MFMAs below
            pa0 = *(const uint4*)(Arow0 + k0 + 32);
            pa1 = *(const uint4*)(Arow1 + k0 + 32);
            pb0 = *(const uint4*)(Brow0 + k0 + 32);
            pb1 = *(const uint4*)(Brow1 + k0 + 32);
        }
        short8 af[4], bf[4];
#pragma unroll
        for (int mi = 0; mi < 4; mi++)
            af[mi] = *(const short8*)(&As[(mw + mi * 16 + l15) * 40 + quad * 8]);
#pragma unroll
        for (int ni = 0; ni < 4; ni++)
            bf[ni] = *(const short8*)(&Bs[(nw + ni * 16 + l15) * 40 + quad * 8]);
#pragma unroll
        for (int mi = 0; mi < 4; mi++)
#pragma unroll
            for (int ni = 0; ni < 4; ni++)
                acc[mi][ni] = __builtin_amdgcn_mfma_f32_16x16x32_bf16(af[mi], bf[ni],
                                                                      acc[mi][ni], 0, 0, 0);
    }

#pragma unroll
    for (int mi = 0; mi < 4; mi++) {
#pragma unroll
        for (int ni = 0; ni < 4; ni++) {
            int j = colBase + nw + ni * 16 + l15;
#pragma unroll
            for (int reg = 0; reg < 4; reg++) {
                int r = rowBase + mw + mi * 16 + quad * 4 + reg;
                out[(size_t)r * CM + j] = acc[mi][ni][reg];
            }
        }
    }
}

extern "C" void kernel_launch(void* const* d_in, const int* in_sizes, int n_in,
                              void* d_out, int out_size, void* d_ws, size_t ws_size,
                              hipStream_t stream) {
    const float* x      = (const float*)d_in[0];
    const float* sinp   = (const float*)d_in[1];
    const float* cosp   = (const float*)d_in[2];
    const float* W_qkv  = (const float*)d_in[3];
    const float* W_proj = (const float*)d_in[4];
    float* out = (float*)d_out;

    char* ws = (char*)d_ws;
    size_t off = 0;
    u16* x_bf   = (u16*)(ws + off); off += (size_t)MROWS * CM * 2;   // 32 MB (reused as y)
    u16* wqkvT  = (u16*)(ws + off); off += (size_t)NQKV * CM * 2;    // 24 MB
    u16* wprojT = (u16*)(ws + off); off += (size_t)CM * CM * 2;      //  8 MB
    u16* q_ws   = (u16*)(ws + off); off += (size_t)MROWS * CM * 2;   // 32 MB
    u16* k_ws   = (u16*)(ws + off); off += (size_t)MROWS * CM * 2;   // 32 MB
    u16* v_ws   = (u16*)(ws + off); off += (size_t)MROWS * CM * 2;   // 32 MB ([b][h][d][t])
    u16* y_bf   = x_bf;   // x dead after qkv GEMM

    convert_x_kernel<<<(MROWS * CM) / (256 * 8), 256, 0, stream>>>(x, x_bf);
    transpose_bf_kernel<<<dim3(NQKV / 32, CM / 32), dim3(32, 8), 0, stream>>>(W_qkv, wqkvT, CM, NQKV);
    transpose_bf_kernel<<<dim3(CM / 32, CM / 32), dim3(32, 8), 0, stream>>>(W_proj, wprojT, CM, CM);
    gemm_qkv_rope<<<(NQKV / 128) * (MROWS / 128), 256, 0, stream>>>(x_bf, wqkvT, sinp, cosp,
                                                                    q_ws, k_ws, v_ws);
    attn_kernel<<<(TSEQ / 128) * 64, 256, 0, stream>>>(q_ws, k_ws, v_ws, y_bf);
    gemm_proj<<<(CM / 128) * (MROWS / 128), 256, 0, stream>>>(y_bf, wprojT, out);
}

// Round 4
// 733.986 us; speedup vs baseline: 1.0236x; 1.0236x over previous
//
#include <hip/hip_runtime.h>
#include <hip/hip_bf16.h>
#include <stdint.h>

typedef uint32_t u32;
typedef uint16_t u16;
typedef __attribute__((ext_vector_type(8))) short short8;
typedef __attribute__((ext_vector_type(4))) float floatx4;

#define NH 16
#define HD 128
#define TSEQ 2048
#define NB 4
#define CM 2048
#define MROWS (NB*TSEQ)      // 8192
#define NQKV (3*CM)          // 6144

__device__ __forceinline__ u16 f2bf(float f) {
    union { float f; u32 u; } v; v.f = f;
    return (u16)((v.u + 0x7fffu + ((v.u >> 16) & 1u)) >> 16);
}

// ---------------- conversion kernels ----------------
__global__ __launch_bounds__(256) void convert_x_kernel(const float* __restrict__ in,
                                                        u16* __restrict__ out) {
    int idx = (blockIdx.x * 256 + threadIdx.x) * 8;
    float4 a = *(const float4*)(in + idx);
    float4 b = *(const float4*)(in + idx + 4);
    union { u16 s[8]; uint4 v; } o;
    o.s[0] = f2bf(a.x); o.s[1] = f2bf(a.y); o.s[2] = f2bf(a.z); o.s[3] = f2bf(a.w);
    o.s[4] = f2bf(b.x); o.s[5] = f2bf(b.y); o.s[6] = f2bf(b.z); o.s[7] = f2bf(b.w);
    *(uint4*)(out + idx) = o.v;
}

// in: [R][Cn] fp32 row-major  ->  out: [Cn][R] bf16 row-major
__global__ __launch_bounds__(256) void transpose_bf_kernel(const float* __restrict__ in,
                                                           u16* __restrict__ out,
                                                           int R, int Cn) {
    __shared__ float tile[32][33];
    int tx = threadIdx.x, ty = threadIdx.y;
    int c0 = blockIdx.x * 32, r0 = blockIdx.y * 32;
#pragma unroll
    for (int i = 0; i < 4; i++)
        tile[ty + i * 8][tx] = in[(size_t)(r0 + ty + i * 8) * Cn + c0 + tx];
    __syncthreads();
#pragma unroll
    for (int i = 0; i < 4; i++)
        out[(size_t)(c0 + ty + i * 8) * R + r0 + tx] = f2bf(tile[tx][ty + i * 8]);
}

// ---------------- QKV GEMM with fused RoPE + scatter ----------------
__global__ __launch_bounds__(256, 2) void gemm_qkv_rope(const u16* __restrict__ A,
                                                        const u16* __restrict__ BT,
                                                        const float* __restrict__ sinp,
                                                        const float* __restrict__ cosp,
                                                        u16* __restrict__ q_ws,
                                                        u16* __restrict__ k_ws,
                                                        u16* __restrict__ v_ws) {
    __shared__ u16 As[128 * 40];
    __shared__ u16 Bs[128 * 40];
    int tid = threadIdx.x;
    int w = tid >> 6, lane = tid & 63, quad = lane >> 4, l15 = lane & 15;
    int mw = (w >> 1) * 64, nw = (w & 1) * 64;
    int blk = blockIdx.x;
    int xcd = blk & 7, idx8 = blk >> 3;           // idx8: 0..383
    int rowBase = (xcd * 8 + (idx8 & 7)) * 128;   // row tile 0..63
    int colBase = (idx8 >> 3) * 128;              // col tile 0..47

    floatx4 acc[4][4];
#pragma unroll
    for (int mi = 0; mi < 4; mi++)
#pragma unroll
        for (int ni = 0; ni < 4; ni++) acc[mi][ni] = (floatx4){0.f, 0.f, 0.f, 0.f};

    int r0s = tid >> 2, c8s = (tid & 3) * 8;      // p=0 slice
    int r1s = (tid + 256) >> 2;                   // p=1 slice (same c8s)
    const u16* Arow0 = A + (size_t)(rowBase + r0s) * CM + c8s;
    const u16* Arow1 = A + (size_t)(rowBase + r1s) * CM + c8s;
    const u16* Brow0 = BT + (size_t)(colBase + r0s) * CM + c8s;
    const u16* Brow1 = BT + (size_t)(colBase + r1s) * CM + c8s;

    uint4 pa0 = *(const uint4*)(Arow0), pa1 = *(const uint4*)(Arow1);
    uint4 pb0 = *(const uint4*)(Brow0), pb1 = *(const uint4*)(Brow1);

    for (int k0 = 0; k0 < CM; k0 += 32) {
        __syncthreads();
        *(uint4*)(&As[r0s * 40 + c8s]) = pa0;
        *(uint4*)(&As[r1s * 40 + c8s]) = pa1;
        *(uint4*)(&Bs[r0s * 40 + c8s]) = pb0;
        *(uint4*)(&Bs[r1s * 40 + c8s]) = pb1;
        __syncthreads();
        if (k0 + 32 < CM) {   // prefetch next K-slab; latency overlaps MFMAs below
            pa0 = *(const uint4*)(Arow0 + k0 + 32);
            pa1 = *(const uint4*)(Arow1 + k0 + 32);
            pb0 = *(const uint4*)(Brow0 + k0 + 32);
            pb1 = *(const uint4*)(Brow1 + k0 + 32);
        }
        short8 af[4], bf[4];
#pragma unroll
        for (int mi = 0; mi < 4; mi++)
            af[mi] = *(const short8*)(&As[(mw + mi * 16 + l15) * 40 + quad * 8]);
#pragma unroll
        for (int ni = 0; ni < 4; ni++)
            bf[ni] = *(const short8*)(&Bs[(nw + ni * 16 + l15) * 40 + quad * 8]);
#pragma unroll
        for (int mi = 0; mi < 4; mi++)
#pragma unroll
            for (int ni = 0; ni < 4; ni++)
                acc[mi][ni] = __builtin_amdgcn_mfma_f32_16x16x32_bf16(af[mi], bf[ni],
                                                                      acc[mi][ni], 0, 0, 0);
    }

    const float inv_sqrt_hd = 0.08838834764831845f;
#pragma unroll
    for (int mi = 0; mi < 4; mi++) {
#pragma unroll
        for (int ni = 0; ni < 4; ni++) {
            int j = colBase + nw + ni * 16 + l15;
            int sec = j >> 11;
            int jj = j & 2047;
            int h = jj >> 7, d = jj & 127;
            if (sec == 2) {
                // V: pack 4 consecutive-t bf16, transposed layout [b][h][d][t]
                int r0 = rowBase + mw + mi * 16 + quad * 4;
                int b = r0 >> 11, t0 = r0 & 2047;
                union { u16 s[4]; uint2 v; } pk;
#pragma unroll
                for (int reg = 0; reg < 4; reg++) pk.s[reg] = f2bf(acc[mi][ni][reg]);
                *(uint2*)(&v_ws[((size_t)(b * NH + h) * HD + d) * TSEQ + t0]) = pk.v;
            } else {
#pragma unroll
                for (int reg = 0; reg < 4; reg++) {
                    int r = rowBase + mw + mi * 16 + quad * 4 + reg;
                    int b = r >> 11, t = r & 2047;
                    float v = acc[mi][ni][reg];
                    float partner = __shfl_xor(v, 1, 64);
                    size_t dsti = (size_t)((b * NH + h) * TSEQ + t) * HD + d;
                    float s = sinp[t * HD + d], c = cosp[t * HD + d];
                    float o = v * c + ((d & 1) ? partner * s : -partner * s);
                    if (sec == 0) o *= inv_sqrt_hd;
                    ((sec == 0) ? q_ws : k_ws)[dsti] = f2bf(o);
                }
            }
        }
    }
}

// ---------------- flash attention (causal, no-max softmax) ----------------
// 8 waves x 16 q-rows (512 threads). Round-3 evidence: with 4 waves x 32 rows
// the kernel was latency-bound (MfmaUtil 10%, VALU 17%, HBM 10%, dur invariant
// to a 2.5x traffic change) at ~1 wave/SIMD resident. Halving per-wave state
// (O 64->32, qf 32->16, S 32->16 regs) and doubling waves/block raises
// resident waves/CU 2-4x and halves the exposed per-iter critical path.
// Staging fully coalesced; LDS XOR-swizzled; prefetch after second barrier.
// LDS: smem 32KB = Q stage, then Ks [16][64][8] + Vt [8][128][8]; Ps [128][72]
__global__ __launch_bounds__(512, 1) void attn_kernel(const u16* __restrict__ q_ws,
                                                      const u16* __restrict__ k_ws,
                                                      const u16* __restrict__ vt_ws,
                                                      u16* __restrict__ y_bf) {
    __shared__ u16 smem[16 * 1024];   // 32 KB
    __shared__ u16 Ps[128 * 72];      // 18.4 KB
    u16* Ks = smem;                   // [s=0..15][key^s7][8]
    u16* Vt = smem + 8192;            // [s=0..7][d^s][8]
    int tid = threadIdx.x;
    int w = tid >> 6, lane = tid & 63, quad = lane >> 4, l15 = lane & 15;
    int qt = 15 - (blockIdx.x >> 6);   // qt slow index: big tiles dispatch first
    int bh = blockIdx.x & 63;
    int b = bh >> 4, h = bh & 15;
    const u16* Qg = q_ws + (size_t)bh * TSEQ * HD;
    const u16* Kg = k_ws + (size_t)bh * TSEQ * HD;
    const u16* Vg = vt_ws + (size_t)bh * HD * TSEQ;

    // issue tile-0 K/V loads first (latency hides under Q staging below)
    uint4 kreg[2], vreg[2];
#pragma unroll
    for (int j = 0; j < 2; j++) {
        int idx = j * 512 + tid;
        int key = idx >> 4, s = idx & 15;
        kreg[j] = *(const uint4*)(Kg + (size_t)key * HD + s * 8);
    }
#pragma unroll
    for (int j = 0; j < 2; j++) {
        int idx = j * 512 + tid;
        int d = idx >> 3, s = idx & 7;
        vreg[j] = *(const uint4*)(Vg + (size_t)d * TSEQ + s * 8);
    }

    // stage Q tile (128x128) through smem, coalesced, then read fragments
#pragma unroll
    for (int j = 0; j < 4; j++) {
        int idx = j * 512 + tid;
        int row = idx >> 4, s = idx & 15;
        uint4 qv = *(const uint4*)(Qg + (size_t)(qt * 128 + row) * HD + s * 8);
        *(uint4*)(&smem[s * 1024 + ((row ^ (s & 7)) * 8)]) = qv;
    }
    __syncthreads();
    short8 qf[4];
#pragma unroll
    for (int kk = 0; kk < 4; kk++) {
        int row = w * 16 + l15;
        int s = kk * 4 + quad;
        qf[kk] = *(const short8*)(&smem[s * 1024 + ((row ^ (s & 7)) * 8)]);
    }
    // loop-top barrier protects smem reuse (Q -> Ks/Vt)

    floatx4 O[8];
#pragma unroll
    for (int f = 0; f < 8; f++) O[f] = (floatx4){0.f, 0.f, 0.f, 0.f};
    float l_i[4];
#pragma unroll
    for (int g = 0; g < 4; g++) l_i[g] = 0.f;

    int ktmax = 2 * qt + 1;
    for (int kt = 0; kt <= ktmax; kt++) {
        __syncthreads();
#pragma unroll
        for (int j = 0; j < 2; j++) {
            int idx = j * 512 + tid;
            int key = idx >> 4, s = idx & 15;
            *(uint4*)(&Ks[s * 512 + ((key ^ (s & 7)) * 8)]) = kreg[j];
        }
#pragma unroll
        for (int j = 0; j < 2; j++) {
            int idx = j * 512 + tid;
            int d = idx >> 3, s = idx & 7;
            *(uint4*)(&Vt[s * 1024 + ((d ^ s) * 8)]) = vreg[j];
        }
        __syncthreads();
        if (kt < ktmax) {   // prefetch next tile; overlaps compute below
            const u16* Ktg = Kg + (size_t)((kt + 1) * 64) * HD;
            const u16* Vtg = Vg + (kt + 1) * 64;
#pragma unroll
            for (int j = 0; j < 2; j++) {
                int idx = j * 512 + tid;
                int key = idx >> 4, s = idx & 15;
                kreg[j] = *(const uint4*)(Ktg + (size_t)key * HD + s * 8);
            }
#pragma unroll
            for (int j = 0; j < 2; j++) {
                int idx = j * 512 + tid;
                int d = idx >> 3, s = idx & 7;
                vreg[j] = *(const uint4*)(Vtg + (size_t)d * TSEQ + s * 8);
            }
        }

        // S = Q K^T : rows = this wave's 16 queries, cols = 64 keys
        floatx4 S[4];
#pragma unroll
        for (int nf = 0; nf < 4; nf++) {
            short8 bb[4];
#pragma unroll
            for (int kk = 0; kk < 4; kk++) {
                int s = kk * 4 + quad;
                int key = nf * 16 + l15;
                bb[kk] = *(const short8*)(&Ks[s * 512 + ((key ^ (s & 7)) * 8)]);
            }
            floatx4 a4 = (floatx4){0.f, 0.f, 0.f, 0.f};
#pragma unroll
            for (int kk = 0; kk < 4; kk++)
                a4 = __builtin_amdgcn_mfma_f32_16x16x32_bf16(qf[kk], bb[kk], a4, 0, 0, 0);
            S[nf] = a4;
        }
        if (kt >= 2 * qt) {   // diagonal region: mask key > query (exp(-1e4) == 0)
#pragma unroll
            for (int nf = 0; nf < 4; nf++) {
                int key = kt * 64 + nf * 16 + l15;
#pragma unroll
                for (int reg = 0; reg < 4; reg++) {
                    int query = qt * 128 + w * 16 + quad * 4 + reg;
                    if (key > query) S[nf][reg] = -1e4f;
                }
            }
        }
        // p = exp(S); accumulate per-lane l; stage P for the PV MFMA
#pragma unroll
        for (int nf = 0; nf < 4; nf++)
#pragma unroll
            for (int reg = 0; reg < 4; reg++) {
                float p = __expf(S[nf][reg]);
                l_i[reg] += p;
                Ps[(w * 16 + quad * 4 + reg) * 72 + nf * 16 + l15] = f2bf(p);
            }
        // O += P V  (Ps rows produced & consumed by same wave; no barrier needed)
        short8 pa[2];
#pragma unroll
        for (int kk = 0; kk < 2; kk++)
            pa[kk] = *(const short8*)(&Ps[(w * 16 + l15) * 72 + kk * 32 + quad * 8]);
#pragma unroll
        for (int f = 0; f < 8; f++) {
            short8 vb[2];
#pragma unroll
            for (int kk = 0; kk < 2; kk++) {
                int s = kk * 4 + quad;
                int d = f * 16 + l15;
                vb[kk] = *(const short8*)(&Vt[s * 1024 + ((d ^ s) * 8)]);
            }
#pragma unroll
            for (int kk = 0; kk < 2; kk++)
                O[f] = __builtin_amdgcn_mfma_f32_16x16x32_bf16(pa[kk], vb[kk], O[f], 0, 0, 0);
        }
    }

    float inv[4];
#pragma unroll
    for (int reg = 0; reg < 4; reg++) {
        float l = l_i[reg];
#pragma unroll
        for (int off = 1; off < 16; off <<= 1) l += __shfl_xor(l, off, 64);
        inv[reg] = 1.0f / l;
    }
#pragma unroll
    for (int f = 0; f < 8; f++)
#pragma unroll
        for (int reg = 0; reg < 4; reg++) {
            int t = qt * 128 + w * 16 + quad * 4 + reg;
            int col = h * HD + f * 16 + l15;
            y_bf[(size_t)(b * TSEQ + t) * CM + col] = f2bf(O[f][reg] * inv[reg]);
        }
}

// ---------------- projection GEMM ----------------
__global__ __launch_bounds__(256, 2) void gemm_proj(const u16* __restrict__ A,
                                                    const u16* __restrict__ BT,
                                                    float* __restrict__ out) {
    __shared__ u16 As[128 * 40];
    __shared__ u16 Bs[128 * 40];
    int tid = threadIdx.x;
    int w = tid >> 6, lane = tid & 63, quad = lane >> 4, l15 = lane & 15;
    int mw = (w >> 1) * 64, nw = (w & 1) * 64;
    int blk = blockIdx.x;
    int xcd = blk & 7, idx8 = blk >> 3;           // idx8: 0..127
    int rowBase = (xcd * 8 + (idx8 & 7)) * 128;   // row tile 0..63
    int colBase = (idx8 >> 3) * 128;              // col tile 0..15

    floatx4 acc[4][4];
#pragma unroll
    for (int mi = 0; mi < 4; mi++)
#pragma unroll
        for (int ni = 0; ni < 4; ni++) acc[mi][ni] = (floatx4){0.f, 0.f, 0.f, 0.f};

    int r0s = tid >> 2, c8s = (tid & 3) * 8;
    int r1s = (tid + 256) >> 2;
    const u16* Arow0 = A + (size_t)(rowBase + r0s) * CM + c8s;
    const u16* Arow1 = A + (size_t)(rowBase + r1s) * CM + c8s;
    const u16* Brow0 = BT + (size_t)(colBase + r0s) * CM + c8s;
    const u16* Brow1 = BT + (size_t)(colBase + r1s) * CM + c8s;

    uint4 pa0 = *(const uint4*)(Arow0), pa1 = *(const uint4*)(Arow1);
    uint4 pb0 = *(const uint4*)(Brow0), pb1 = *(const uint4*)(Brow1);

    for (int k0 = 0; k0 < CM; k0 += 32) {
        __syncthreads();
        *(uint4*)(&As[r0s * 40 + c8s]) = pa0;
        *(uint4*)(&As[r1s * 40 + c8s]) = pa1;
        *(uint4*)(&Bs[r0s * 40 + c8s]) = pb0;
        *(uint4*)(&Bs[r1s * 40 + c8s]) = pb1;
        __syncthreads();
        if (k0 + 32 < CM) {   // prefetch next K-slab; latency overlaps MFMAs below
            pa0 = *(const uint4*)(Arow0 + k0 + 32);
            pa1 = *(const uint4*)(Arow1 + k0 + 32);
            pb0 = *(const uint4*)(Brow0 + k0 + 32);
            pb1 = *(const uint4*)(Brow1 + k0 + 32);
        }
        short8 af[4], bf[4];
#pragma unroll
        for (int mi = 0; mi < 4; mi++)
            af[mi] = *(const short8*)(&As[(mw + mi * 16 + l15) * 40 + quad * 8]);
#pragma unroll
        for (int ni = 0; ni < 4; ni++)
            bf[ni] = *(const short8*)(&Bs[(nw + ni * 16 + l15) * 40 + quad * 8]);
#pragma unroll
        for (int mi = 0; mi < 4; mi++)
#pragma unroll
            for (int ni = 0; ni < 4; ni++)
                acc[mi][ni] = __builtin_amdgcn_mfma_f32_16x16x32_bf16(af[mi], bf[ni],
                                                                      acc[mi][ni], 0, 0, 0);
    }

#pragma unroll
    for (int mi = 0; mi < 4; mi++) {
#pragma unroll
        for (int ni = 0; ni < 4; ni++) {
            int j = colBase + nw + ni * 16 + l15;
#pragma unroll
            for (int reg = 0; reg < 4; reg++) {
                int r = rowBase + mw + mi * 16 + quad * 4 + reg;
                out[(size_t)r * CM + j] = acc[mi][ni][reg];
            }
        }
    }
}

extern "C" void kernel_launch(void* const* d_in, const int* in_sizes, int n_in,
                              void* d_out, int out_size, void* d_ws, size_t ws_size,
                              hipStream_t stream) {
    const float* x      = (const float*)d_in[0];
    const float* sinp   = (const float*)d_in[1];
    const float* cosp   = (const float*)d_in[2];
    const float* W_qkv  = (const float*)d_in[3];
    const float* W_proj = (const float*)d_in[4];
    float* out = (float*)d_out;

    char* ws = (char*)d_ws;
    size_t off = 0;
    u16* x_bf   = (u16*)(ws + off); off += (size_t)MROWS * CM * 2;   // 32 MB (reused as y)
    u16* wqkvT  = (u16*)(ws + off); off += (size_t)NQKV * CM * 2;    // 24 MB
    u16* wprojT = (u16*)(ws + off); off += (size_t)CM * CM * 2;      //  8 MB
    u16* q_ws   = (u16*)(ws + off); off += (size_t)MROWS * CM * 2;   // 32 MB
    u16* k_ws   = (u16*)(ws + off); off += (size_t)MROWS * CM * 2;   // 32 MB
    u16* v_ws   = (u16*)(ws + off); off += (size_t)MROWS * CM * 2;   // 32 MB ([b][h][d][t])
    u16* y_bf   = x_bf;   // x dead after qkv GEMM

    convert_x_kernel<<<(MROWS * CM) / (256 * 8), 256, 0, stream>>>(x, x_bf);
    transpose_bf_kernel<<<dim3(NQKV / 32, CM / 32), dim3(32, 8), 0, stream>>>(W_qkv, wqkvT, CM, NQKV);
    transpose_bf_kernel<<<dim3(CM / 32, CM / 32), dim3(32, 8), 0, stream>>>(W_proj, wprojT, CM, CM);
    gemm_qkv_rope<<<(NQKV / 128) * (MROWS / 128), 256, 0, stream>>>(x_bf, wqkvT, sinp, cosp,
                                                                    q_ws, k_ws, v_ws);
    attn_kernel<<<(TSEQ / 128) * 64, 512, 0, stream>>>(q_ws, k_ws, v_ws, y_bf);
    gemm_proj<<<(CM / 128) * (MROWS / 128), 256, 0, stream>>>(y_bf, wprojT, out);
}

// Round 5
// 718.361 us; speedup vs baseline: 1.0459x; 1.0218x over previous
//
#include <hip/hip_runtime.h>
#include <hip/hip_bf16.h>
#include <stdint.h>

typedef uint32_t u32;
typedef uint16_t u16;
typedef __attribute__((ext_vector_type(8))) short short8;
typedef __attribute__((ext_vector_type(4))) float floatx4;

#define NH 16
#define HD 128
#define TSEQ 2048
#define NB 4
#define CM 2048
#define MROWS (NB*TSEQ)      // 8192
#define NQKV (3*CM)          // 6144

__device__ __forceinline__ u16 f2bf(float f) {
    union { float f; u32 u; } v; v.f = f;
    return (u16)((v.u + 0x7fffu + ((v.u >> 16) & 1u)) >> 16);
}

// async global->LDS, 16B per lane. LDS dest is wave-uniform base + lane*16.
__device__ __forceinline__ void gload16(const u16* g, u16* l) {
    __builtin_amdgcn_global_load_lds(
        (const __attribute__((address_space(1))) void*)g,
        (__attribute__((address_space(3))) void*)l, 16, 0, 0);
}

// ---------------- conversion kernels ----------------
__global__ __launch_bounds__(256) void convert_x_kernel(const float* __restrict__ in,
                                                        u16* __restrict__ out) {
    int idx = (blockIdx.x * 256 + threadIdx.x) * 8;
    float4 a = *(const float4*)(in + idx);
    float4 b = *(const float4*)(in + idx + 4);
    union { u16 s[8]; uint4 v; } o;
    o.s[0] = f2bf(a.x); o.s[1] = f2bf(a.y); o.s[2] = f2bf(a.z); o.s[3] = f2bf(a.w);
    o.s[4] = f2bf(b.x); o.s[5] = f2bf(b.y); o.s[6] = f2bf(b.z); o.s[7] = f2bf(b.w);
    *(uint4*)(out + idx) = o.v;
}

// in: [R][Cn] fp32 row-major  ->  out: [Cn][R] bf16 row-major
__global__ __launch_bounds__(256) void transpose_bf_kernel(const float* __restrict__ in,
                                                           u16* __restrict__ out,
                                                           int R, int Cn) {
    __shared__ float tile[32][33];
    int tx = threadIdx.x, ty = threadIdx.y;
    int c0 = blockIdx.x * 32, r0 = blockIdx.y * 32;
#pragma unroll
    for (int i = 0; i < 4; i++)
        tile[ty + i * 8][tx] = in[(size_t)(r0 + ty + i * 8) * Cn + c0 + tx];
    __syncthreads();
#pragma unroll
    for (int i = 0; i < 4; i++)
        out[(size_t)(c0 + ty + i * 8) * R + r0 + tx] = f2bf(tile[tx][ty + i * 8]);
}

// ---------------- QKV GEMM with fused RoPE + scatter ----------------
// m97-style staging: global_load_lds width=16, linear [128][32] LDS, swizzle
// applied BOTH on the per-lane global source and on the ds_read side
// (pb = blk ^ ((row>>1)&3)): balanced 2-lanes-per-16B-slot read = conflict-free.
// Single-buffered 2-barrier loop (m97: 874-912 TF at this tile on gfx950).
__global__ __launch_bounds__(256, 2) void gemm_qkv_rope(const u16* __restrict__ A,
                                                        const u16* __restrict__ BT,
                                                        const float* __restrict__ sinp,
                                                        const float* __restrict__ cosp,
                                                        u16* __restrict__ q_ws,
                                                        u16* __restrict__ k_ws,
                                                        u16* __restrict__ v_ws) {
    __shared__ u16 As[128 * 32];
    __shared__ u16 Bs[128 * 32];
    int tid = threadIdx.x;
    int w = tid >> 6, lane = tid & 63, quad = lane >> 4, l15 = lane & 15;
    int mw = (w >> 1) * 64, nw = (w & 1) * 64;
    int blk = blockIdx.x;
    int xcd = blk & 7, idx8 = blk >> 3;           // idx8: 0..383
    int rowBase = (xcd * 8 + (idx8 & 7)) * 128;   // row tile 0..63
    int colBase = (idx8 >> 3) * 128;              // col tile 0..47

    floatx4 acc[4][4];
#pragma unroll
    for (int mi = 0; mi < 4; mi++)
#pragma unroll
        for (int ni = 0; ni < 4; ni++) acc[mi][ni] = (floatx4){0.f, 0.f, 0.f, 0.f};

    // staging source: chunk i covers LDS rows (w*2+i)*16 + lane/4, phys blk lane&3;
    // source column block inverse-swizzled so LDS slot (row,pb) holds logical
    // blk = pb ^ ((row>>1)&3).
    const u16* Asrc[2]; const u16* Bsrc[2];
#pragma unroll
    for (int i = 0; i < 2; i++) {
        int row = (w * 2 + i) * 16 + (lane >> 2);
        int cb  = (lane & 3) ^ ((row >> 1) & 3);
        Asrc[i] = A + (size_t)(rowBase + row) * CM + cb * 8;
        Bsrc[i] = BT + (size_t)(colBase + row) * CM + cb * 8;
    }

    for (int k0 = 0; k0 < CM; k0 += 32) {
#pragma unroll
        for (int i = 0; i < 2; i++) {
            gload16(Asrc[i] + k0, &As[(w * 2 + i) * 512]);
            gload16(Bsrc[i] + k0, &Bs[(w * 2 + i) * 512]);
        }
        __syncthreads();   // vmcnt(0) drain: staged data visible
        short8 af[4], bf[4];
#pragma unroll
        for (int mi = 0; mi < 4; mi++) {
            int row = mw + mi * 16 + l15;
            int pb = quad ^ ((row >> 1) & 3);
            af[mi] = *(const short8*)(&As[row * 32 + pb * 8]);
        }
#pragma unroll
        for (int ni = 0; ni < 4; ni++) {
            int row = nw + ni * 16 + l15;
            int pb = quad ^ ((row >> 1) & 3);
            bf[ni] = *(const short8*)(&Bs[row * 32 + pb * 8]);
        }
#pragma unroll
        for (int mi = 0; mi < 4; mi++)
#pragma unroll
            for (int ni = 0; ni < 4; ni++)
                acc[mi][ni] = __builtin_amdgcn_mfma_f32_16x16x32_bf16(af[mi], bf[ni],
                                                                      acc[mi][ni], 0, 0, 0);
        __syncthreads();   // protect LDS overwrite by next iteration's stage
    }

    const float inv_sqrt_hd = 0.08838834764831845f;
#pragma unroll
    for (int mi = 0; mi < 4; mi++) {
#pragma unroll
        for (int ni = 0; ni < 4; ni++) {
            int j = colBase + nw + ni * 16 + l15;
            int sec = j >> 11;
            int jj = j & 2047;
            int h = jj >> 7, d = jj & 127;
            if (sec == 2) {
                // V: pack 4 consecutive-t bf16, transposed layout [b][h][d][t]
                int r0 = rowBase + mw + mi * 16 + quad * 4;
                int b = r0 >> 11, t0 = r0 & 2047;
                union { u16 s[4]; uint2 v; } pk;
#pragma unroll
                for (int reg = 0; reg < 4; reg++) pk.s[reg] = f2bf(acc[mi][ni][reg]);
                *(uint2*)(&v_ws[((size_t)(b * NH + h) * HD + d) * TSEQ + t0]) = pk.v;
            } else {
#pragma unroll
                for (int reg = 0; reg < 4; reg++) {
                    int r = rowBase + mw + mi * 16 + quad * 4 + reg;
                    int b = r >> 11, t = r & 2047;
                    float v = acc[mi][ni][reg];
                    float partner = __shfl_xor(v, 1, 64);
                    size_t dsti = (size_t)((b * NH + h) * TSEQ + t) * HD + d;
                    float s = sinp[t * HD + d], c = cosp[t * HD + d];
                    float o = v * c + ((d & 1) ? partner * s : -partner * s);
                    if (sec == 0) o *= inv_sqrt_hd;
                    ((sec == 0) ? q_ws : k_ws)[dsti] = f2bf(o);
                }
            }
        }
    }
}

// ---------------- flash attention (causal, no-max softmax) ----------------
// 8 waves x 16 q-rows (512 threads). Round-3 evidence: with 4 waves x 32 rows
// the kernel was latency-bound (MfmaUtil 10%, VALU 17%, HBM 10%, dur invariant
// to a 2.5x traffic change) at ~1 wave/SIMD resident. Halving per-wave state
// and doubling waves/block raised resident waves and dropped attn below the
// gemm rows (<278us in round-4 counters).
// Staging fully coalesced; LDS XOR-swizzled; prefetch after second barrier.
// LDS: smem 32KB = Q stage, then Ks [16][64][8] + Vt [8][128][8]; Ps [128][72]
__global__ __launch_bounds__(512, 1) void attn_kernel(const u16* __restrict__ q_ws,
                                                      const u16* __restrict__ k_ws,
                                                      const u16* __restrict__ vt_ws,
                                                      u16* __restrict__ y_bf) {
    __shared__ u16 smem[16 * 1024];   // 32 KB
    __shared__ u16 Ps[128 * 72];      // 18.4 KB
    u16* Ks = smem;                   // [s=0..15][key^s7][8]
    u16* Vt = smem + 8192;            // [s=0..7][d^s][8]
    int tid = threadIdx.x;
    int w = tid >> 6, lane = tid & 63, quad = lane >> 4, l15 = lane & 15;
    int qt = 15 - (blockIdx.x >> 6);   // qt slow index: big tiles dispatch first
    int bh = blockIdx.x & 63;
    int b = bh >> 4, h = bh & 15;
    const u16* Qg = q_ws + (size_t)bh * TSEQ * HD;
    const u16* Kg = k_ws + (size_t)bh * TSEQ * HD;
    const u16* Vg = vt_ws + (size_t)bh * HD * TSEQ;

    // issue tile-0 K/V loads first (latency hides under Q staging below)
    uint4 kreg[2], vreg[2];
#pragma unroll
    for (int j = 0; j < 2; j++) {
        int idx = j * 512 + tid;
        int key = idx >> 4, s = idx & 15;
        kreg[j] = *(const uint4*)(Kg + (size_t)key * HD + s * 8);
    }
#pragma unroll
    for (int j = 0; j < 2; j++) {
        int idx = j * 512 + tid;
        int d = idx >> 3, s = idx & 7;
        vreg[j] = *(const uint4*)(Vg + (size_t)d * TSEQ + s * 8);
    }

    // stage Q tile (128x128) through smem, coalesced, then read fragments
#pragma unroll
    for (int j = 0; j < 4; j++) {
        int idx = j * 512 + tid;
        int row = idx >> 4, s = idx & 15;
        uint4 qv = *(const uint4*)(Qg + (size_t)(qt * 128 + row) * HD + s * 8);
        *(uint4*)(&smem[s * 1024 + ((row ^ (s & 7)) * 8)]) = qv;
    }
    __syncthreads();
    short8 qf[4];
#pragma unroll
    for (int kk = 0; kk < 4; kk++) {
        int row = w * 16 + l15;
        int s = kk * 4 + quad;
        qf[kk] = *(const short8*)(&smem[s * 1024 + ((row ^ (s & 7)) * 8)]);
    }
    // loop-top barrier protects smem reuse (Q -> Ks/Vt)

    floatx4 O[8];
#pragma unroll
    for (int f = 0; f < 8; f++) O[f] = (floatx4){0.f, 0.f, 0.f, 0.f};
    float l_i[4];
#pragma unroll
    for (int g = 0; g < 4; g++) l_i[g] = 0.f;

    int ktmax = 2 * qt + 1;
    for (int kt = 0; kt <= ktmax; kt++) {
        __syncthreads();
#pragma unroll
        for (int j = 0; j < 2; j++) {
            int idx = j * 512 + tid;
            int key = idx >> 4, s = idx & 15;
            *(uint4*)(&Ks[s * 512 + ((key ^ (s & 7)) * 8)]) = kreg[j];
        }
#pragma unroll
        for (int j = 0; j < 2; j++) {
            int idx = j * 512 + tid;
            int d = idx >> 3, s = idx & 7;
            *(uint4*)(&Vt[s * 1024 + ((d ^ s) * 8)]) = vreg[j];
        }
        __syncthreads();
        if (kt < ktmax) {   // prefetch next tile; overlaps compute below
            const u16* Ktg = Kg + (size_t)((kt + 1) * 64) * HD;
            const u16* Vtg = Vg + (kt + 1) * 64;
#pragma unroll
            for (int j = 0; j < 2; j++) {
                int idx = j * 512 + tid;
                int key = idx >> 4, s = idx & 15;
                kreg[j] = *(const uint4*)(Ktg + (size_t)key * HD + s * 8);
            }
#pragma unroll
            for (int j = 0; j < 2; j++) {
                int idx = j * 512 + tid;
                int d = idx >> 3, s = idx & 7;
                vreg[j] = *(const uint4*)(Vtg + (size_t)d * TSEQ + s * 8);
            }
        }

        // S = Q K^T : rows = this wave's 16 queries, cols = 64 keys
        floatx4 S[4];
#pragma unroll
        for (int nf = 0; nf < 4; nf++) {
            short8 bb[4];
#pragma unroll
            for (int kk = 0; kk < 4; kk++) {
                int s = kk * 4 + quad;
                int key = nf * 16 + l15;
                bb[kk] = *(const short8*)(&Ks[s * 512 + ((key ^ (s & 7)) * 8)]);
            }
            floatx4 a4 = (floatx4){0.f, 0.f, 0.f, 0.f};
#pragma unroll
            for (int kk = 0; kk < 4; kk++)
                a4 = __builtin_amdgcn_mfma_f32_16x16x32_bf16(qf[kk], bb[kk], a4, 0, 0, 0);
            S[nf] = a4;
        }
        if (kt >= 2 * qt) {   // diagonal region: mask key > query (exp(-1e4) == 0)
#pragma unroll
            for (int nf = 0; nf < 4; nf++) {
                int key = kt * 64 + nf * 16 + l15;
#pragma unroll
                for (int reg = 0; reg < 4; reg++) {
                    int query = qt * 128 + w * 16 + quad * 4 + reg;
                    if (key > query) S[nf][reg] = -1e4f;
                }
            }
        }
        // p = exp(S); accumulate per-lane l; stage P for the PV MFMA
#pragma unroll
        for (int nf = 0; nf < 4; nf++)
#pragma unroll
            for (int reg = 0; reg < 4; reg++) {
                float p = __expf(S[nf][reg]);
                l_i[reg] += p;
                Ps[(w * 16 + quad * 4 + reg) * 72 + nf * 16 + l15] = f2bf(p);
            }
        // O += P V  (Ps rows produced & consumed by same wave; no barrier needed)
        short8 pa[2];
#pragma unroll
        for (int kk = 0; kk < 2; kk++)
            pa[kk] = *(const short8*)(&Ps[(w * 16 + l15) * 72 + kk * 32 + quad * 8]);
#pragma unroll
        for (int f = 0; f < 8; f++) {
            short8 vb[2];
#pragma unroll
            for (int kk = 0; kk < 2; kk++) {
                int s = kk * 4 + quad;
                int d = f * 16 + l15;
                vb[kk] = *(const short8*)(&Vt[s * 1024 + ((d ^ s) * 8)]);
            }
#pragma unroll
            for (int kk = 0; kk < 2; kk++)
                O[f] = __builtin_amdgcn_mfma_f32_16x16x32_bf16(pa[kk], vb[kk], O[f], 0, 0, 0);
        }
    }

    float inv[4];
#pragma unroll
    for (int reg = 0; reg < 4; reg++) {
        float l = l_i[reg];
#pragma unroll
        for (int off = 1; off < 16; off <<= 1) l += __shfl_xor(l, off, 64);
        inv[reg] = 1.0f / l;
    }
#pragma unroll
    for (int f = 0; f < 8; f++)
#pragma unroll
        for (int reg = 0; reg < 4; reg++) {
            int t = qt * 128 + w * 16 + quad * 4 + reg;
            int col = h * HD + f * 16 + l15;
            y_bf[(size_t)(b * TSEQ + t) * CM + col] = f2bf(O[f][reg] * inv[reg]);
        }
}

// ---------------- projection GEMM ----------------
// Same m97-style global_load_lds staging as gemm_qkv_rope.
__global__ __launch_bounds__(256, 2) void gemm_proj(const u16* __restrict__ A,
                                                    const u16* __restrict__ BT,
                                                    float* __restrict__ out) {
    __shared__ u16 As[128 * 32];
    __shared__ u16 Bs[128 * 32];
    int tid = threadIdx.x;
    int w = tid >> 6, lane = tid & 63, quad = lane >> 4, l15 = lane & 15;
    int mw = (w >> 1) * 64, nw = (w & 1) * 64;
    int blk = blockIdx.x;
    int xcd = blk & 7, idx8 = blk >> 3;           // idx8: 0..127
    int rowBase = (xcd * 8 + (idx8 & 7)) * 128;   // row tile 0..63
    int colBase = (idx8 >> 3) * 128;              // col tile 0..15

    floatx4 acc[4][4];
#pragma unroll
    for (int mi = 0; mi < 4; mi++)
#pragma unroll
        for (int ni = 0; ni < 4; ni++) acc[mi][ni] = (floatx4){0.f, 0.f, 0.f, 0.f};

    const u16* Asrc[2]; const u16* Bsrc[2];
#pragma unroll
    for (int i = 0; i < 2; i++) {
        int row = (w * 2 + i) * 16 + (lane >> 2);
        int cb  = (lane & 3) ^ ((row >> 1) & 3);
        Asrc[i] = A + (size_t)(rowBase + row) * CM + cb * 8;
        Bsrc[i] = BT + (size_t)(colBase + row) * CM + cb * 8;
    }

    for (int k0 = 0; k0 < CM; k0 += 32) {
#pragma unroll
        for (int i = 0; i < 2; i++) {
            gload16(Asrc[i] + k0, &As[(w * 2 + i) * 512]);
            gload16(Bsrc[i] + k0, &Bs[(w * 2 + i) * 512]);
        }
        __syncthreads();
        short8 af[4], bf[4];
#pragma unroll
        for (int mi = 0; mi < 4; mi++) {
            int row = mw + mi * 16 + l15;
            int pb = quad ^ ((row >> 1) & 3);
            af[mi] = *(const short8*)(&As[row * 32 + pb * 8]);
        }
#pragma unroll
        for (int ni = 0; ni < 4; ni++) {
            int row = nw + ni * 16 + l15;
            int pb = quad ^ ((row >> 1) & 3);
            bf[ni] = *(const short8*)(&Bs[row * 32 + pb * 8]);
        }
#pragma unroll
        for (int mi = 0; mi < 4; mi++)
#pragma unroll
            for (int ni = 0; ni < 4; ni++)
                acc[mi][ni] = __builtin_amdgcn_mfma_f32_16x16x32_bf16(af[mi], bf[ni],
                                                                      acc[mi][ni], 0, 0, 0);
        __syncthreads();
    }

#pragma unroll
    for (int mi = 0; mi < 4; mi++) {
#pragma unroll
        for (int ni = 0; ni < 4; ni++) {
            int j = colBase + nw + ni * 16 + l15;
#pragma unroll
            for (int reg = 0; reg < 4; reg++) {
                int r = rowBase + mw + mi * 16 + quad * 4 + reg;
                out[(size_t)r * CM + j] = acc[mi][ni][reg];
            }
        }
    }
}

extern "C" void kernel_launch(void* const* d_in, const int* in_sizes, int n_in,
                              void* d_out, int out_size, void* d_ws, size_t ws_size,
                              hipStream_t stream) {
    const float* x      = (const float*)d_in[0];
    const float* sinp   = (const float*)d_in[1];
    const float* cosp   = (const float*)d_in[2];
    const float* W_qkv  = (const float*)d_in[3];
    const float* W_proj = (const float*)d_in[4];
    float* out = (float*)d_out;

    char* ws = (char*)d_ws;
    size_t off = 0;
    u16* x_bf   = (u16*)(ws + off); off += (size_t)MROWS * CM * 2;   // 32 MB (reused as y)
    u16* wqkvT  = (u16*)(ws + off); off += (size_t)NQKV * CM * 2;    // 24 MB
    u16* wprojT = (u16*)(ws + off); off += (size_t)CM * CM * 2;      //  8 MB
    u16* q_ws   = (u16*)(ws + off); off += (size_t)MROWS * CM * 2;   // 32 MB
    u16* k_ws   = (u16*)(ws + off); off += (size_t)MROWS * CM * 2;   // 32 MB
    u16* v_ws   = (u16*)(ws + off); off += (size_t)MROWS * CM * 2;   // 32 MB ([b][h][d][t])
    u16* y_bf   = x_bf;   // x dead after qkv GEMM

    convert_x_kernel<<<(MROWS * CM) / (256 * 8), 256, 0, stream>>>(x, x_bf);
    transpose_bf_kernel<<<dim3(NQKV / 32, CM / 32), dim3(32, 8), 0, stream>>>(W_qkv, wqkvT, CM, NQKV);
    transpose_bf_kernel<<<dim3(CM / 32, CM / 32), dim3(32, 8), 0, stream>>>(W_proj, wprojT, CM, CM);
    gemm_qkv_rope<<<(NQKV / 128) * (MROWS / 128), 256, 0, stream>>>(x_bf, wqkvT, sinp, cosp,
                                                                    q_ws, k_ws, v_ws);
    attn_kernel<<<(TSEQ / 128) * 64, 512, 0, stream>>>(q_ws, k_ws, v_ws, y_bf);
    gemm_proj<<<(CM / 128) * (MROWS / 128), 256, 0, stream>>>(y_bf, wprojT, out);
}

// Round 6
// 656.425 us; speedup vs baseline: 1.1446x; 1.0944x over previous
//
#include <hip/hip_runtime.h>
#include <hip/hip_bf16.h>
#include <stdint.h>

typedef uint32_t u32;
typedef uint16_t u16;
typedef __attribute__((ext_vector_type(8))) short short8;
typedef __attribute__((ext_vector_type(4))) float floatx4;

#define NH 16
#define HD 128
#define TSEQ 2048
#define NB 4
#define CM 2048
#define MROWS (NB*TSEQ)      // 8192
#define NQKV (3*CM)          // 6144

__device__ __forceinline__ u16 f2bf(float f) {
    union { float f; u32 u; } v; v.f = f;
    return (u16)((v.u + 0x7fffu + ((v.u >> 16) & 1u)) >> 16);
}

// async global->LDS, 16B per lane. LDS dest is wave-uniform base + lane*16.
__device__ __forceinline__ void gload16(const u16* g, u16* l) {
    __builtin_amdgcn_global_load_lds(
        (const __attribute__((address_space(1))) void*)g,
        (__attribute__((address_space(3))) void*)l, 16, 0, 0);
}

// ---------------- conversion kernels ----------------
__global__ __launch_bounds__(256) void convert_x_kernel(const float* __restrict__ in,
                                                        u16* __restrict__ out) {
    int idx = (blockIdx.x * 256 + threadIdx.x) * 8;
    float4 a = *(const float4*)(in + idx);
    float4 b = *(const float4*)(in + idx + 4);
    union { u16 s[8]; uint4 v; } o;
    o.s[0] = f2bf(a.x); o.s[1] = f2bf(a.y); o.s[2] = f2bf(a.z); o.s[3] = f2bf(a.w);
    o.s[4] = f2bf(b.x); o.s[5] = f2bf(b.y); o.s[6] = f2bf(b.z); o.s[7] = f2bf(b.w);
    *(uint4*)(out + idx) = o.v;
}

// in: [R][Cn] fp32 row-major  ->  out: [Cn][R] bf16 row-major
__global__ __launch_bounds__(256) void transpose_bf_kernel(const float* __restrict__ in,
                                                           u16* __restrict__ out,
                                                           int R, int Cn) {
    __shared__ float tile[32][33];
    int tx = threadIdx.x, ty = threadIdx.y;
    int c0 = blockIdx.x * 32, r0 = blockIdx.y * 32;
#pragma unroll
    for (int i = 0; i < 4; i++)
        tile[ty + i * 8][tx] = in[(size_t)(r0 + ty + i * 8) * Cn + c0 + tx];
    __syncthreads();
#pragma unroll
    for (int i = 0; i < 4; i++)
        out[(size_t)(c0 + ty + i * 8) * R + r0 + tx] = f2bf(tile[tx][ty + i * 8]);
}

// ---------------- 256x256 / BK=64 / 8-wave deep-phased GEMM core ----------------
// Round-5 evidence: 128-tile 2-barrier structure pinned at ~755 TF (MfmaUtil 34%)
// with conflicts=0 and gload_lds staging -> the vmcnt(0)+syncthreads drain per
// 16 MFMA is the binding constraint (documented m97 ceiling). This core:
//  - 256x256 tile, BK=64, 8 waves (wr=w>>2, wc=w&3), per-wave 128x64 out
//  - LDS 128KB: 2 K-tile buffers x {A0,A1,B0,B1} halves (16KB each)
//  - 4 phases/K-tile: {stage-issue || ds_read frags || raw s_barrier ||
//    setprio(1) 16xMFMA setprio(0)}; ONE vmcnt(0) per K-tile (per 64 MFMA),
//    placed at ph3 so next tile's 8 gload_lds drain under ~3 phases of MFMA.
//  - raw s_barrier (no implicit vmcnt drain); "memory" clobber pins LDS ops.
//  - slot-XOR swizzle (slot ^= row&7): wave64 b128 reads hit the uniform
//    8-lanes/bank-group floor; staging source pre-swizzled, gload dest linear.
__device__ __forceinline__ void gemm256_core(const u16* __restrict__ A,
                                             const u16* __restrict__ BT,
                                             int rowBase, int colBase,
                                             int tid, u16* lds,
                                             floatx4 acc[8][4]) {
    const int w = tid >> 6, lane = tid & 63, quad = lane >> 4, l15 = lane & 15;
    const int wr = w >> 2, wc = w & 3;

    // staging geometry: thread covers rows (j*64 + tid/8) of each 128-row half,
    // 16B chunk (tid&7); logical col-slot = phys ^ (row&7) (inverse swizzle).
    const int srow = tid >> 3;                 // 0..63
    const int sl = (tid & 7) ^ (srow & 7);     // same for j=0/1 (row+64 keeps &7)
    const u16* aSrc[2][2]; const u16* bSrc[2][2];
#pragma unroll
    for (int h = 0; h < 2; h++)
#pragma unroll
        for (int j = 0; j < 2; j++) {
            int r = h * 128 + j * 64 + srow;
            aSrc[h][j] = A  + (size_t)(rowBase + r) * CM + sl * 8;
            bSrc[h][j] = BT + (size_t)(colBase + r) * CM + sl * 8;
        }
    const int wofs = w * 512;   // wave-uniform LDS chunk base (u16)

    // frag-read slots (u16 offset): slot = (kk*4+quad) ^ (row&7), row&7 == l15&7
    const int sA0 = (quad ^ (l15 & 7)) * 8;
    const int sA1 = ((4 + quad) ^ (l15 & 7)) * 8;
    u16* aBase = lds + wr * 8192;                    // + p*32768
    u16* bBase = lds + 16384 + (wc >> 1) * 8192;     // + p*32768
    const int rB0 = (wc & 1) * 64;

#define STAGE_A(q, kt) do { \
    gload16(aSrc[0][0] + (kt) * 64, lds + (q) * 32768 + 0    + 0 * 4096 + wofs); \
    gload16(aSrc[0][1] + (kt) * 64, lds + (q) * 32768 + 0    + 1 * 4096 + wofs); \
    gload16(aSrc[1][0] + (kt) * 64, lds + (q) * 32768 + 8192 + 0 * 4096 + wofs); \
    gload16(aSrc[1][1] + (kt) * 64, lds + (q) * 32768 + 8192 + 1 * 4096 + wofs); \
} while (0)
#define STAGE_B(q, kt) do { \
    gload16(bSrc[0][0] + (kt) * 64, lds + (q) * 32768 + 16384 + 0 * 4096 + wofs); \
    gload16(bSrc[0][1] + (kt) * 64, lds + (q) * 32768 + 16384 + 1 * 4096 + wofs); \
    gload16(bSrc[1][0] + (kt) * 64, lds + (q) * 32768 + 24576 + 0 * 4096 + wofs); \
    gload16(bSrc[1][1] + (kt) * 64, lds + (q) * 32768 + 24576 + 1 * 4096 + wofs); \
} while (0)
#define RAW_BARRIER() asm volatile("s_barrier" ::: "memory")

    // prologue: stage K-tile 0 into buf 0, publish
    STAGE_A(0, 0); STAGE_B(0, 0);
    asm volatile("s_waitcnt vmcnt(0)" ::: "memory");
    RAW_BARRIER();

    const int T = CM / 64;   // 32 K-tiles
    for (int kt = 0; kt < T; kt++) {
        const int p = kt & 1, q = p ^ 1;
        const int pofs = p * 32768;
        const bool pre = (kt + 1 < T);
        short8 af[8], b0, b1;

        // phase 0: stage A(kt+1); read A[kk0] + B[kk0] ni0,1; MFMA ni0,1
        if (pre) STAGE_A(q, kt + 1);
#pragma unroll
        for (int mi = 0; mi < 8; mi++)
            af[mi] = *(const short8*)(aBase + pofs + (mi * 16 + l15) * 64 + sA0);
        b0 = *(const short8*)(bBase + pofs + (rB0 + l15) * 64 + sA0);
        b1 = *(const short8*)(bBase + pofs + (rB0 + 16 + l15) * 64 + sA0);
        RAW_BARRIER();
        __builtin_amdgcn_s_setprio(1);
#pragma unroll
        for (int mi = 0; mi < 8; mi++) {
            acc[mi][0] = __builtin_amdgcn_mfma_f32_16x16x32_bf16(af[mi], b0, acc[mi][0], 0, 0, 0);
            acc[mi][1] = __builtin_amdgcn_mfma_f32_16x16x32_bf16(af[mi], b1, acc[mi][1], 0, 0, 0);
        }
        __builtin_amdgcn_s_setprio(0);

        // phase 1: stage B(kt+1); read B[kk0] ni2,3; MFMA ni2,3
        if (pre) STAGE_B(q, kt + 1);
        b0 = *(const short8*)(bBase + pofs + (rB0 + 32 + l15) * 64 + sA0);
        b1 = *(const short8*)(bBase + pofs + (rB0 + 48 + l15) * 64 + sA0);
        RAW_BARRIER();
        __builtin_amdgcn_s_setprio(1);
#pragma unroll
        for (int mi = 0; mi < 8; mi++) {
            acc[mi][2] = __builtin_amdgcn_mfma_f32_16x16x32_bf16(af[mi], b0, acc[mi][2], 0, 0, 0);
            acc[mi][3] = __builtin_amdgcn_mfma_f32_16x16x32_bf16(af[mi], b1, acc[mi][3], 0, 0, 0);
        }
        __builtin_amdgcn_s_setprio(0);

        // phase 2: read A[kk1] + B[kk1] ni0,1; MFMA ni0,1
#pragma unroll
        for (int mi = 0; mi < 8; mi++)
            af[mi] = *(const short8*)(aBase + pofs + (mi * 16 + l15) * 64 + sA1);
        b0 = *(const short8*)(bBase + pofs + (rB0 + l15) * 64 + sA1);
        b1 = *(const short8*)(bBase + pofs + (rB0 + 16 + l15) * 64 + sA1);
        RAW_BARRIER();
        __builtin_amdgcn_s_setprio(1);
#pragma unroll
        for (int mi = 0; mi < 8; mi++) {
            acc[mi][0] = __builtin_amdgcn_mfma_f32_16x16x32_bf16(af[mi], b0, acc[mi][0], 0, 0, 0);
            acc[mi][1] = __builtin_amdgcn_mfma_f32_16x16x32_bf16(af[mi], b1, acc[mi][1], 0, 0, 0);
        }
        __builtin_amdgcn_s_setprio(0);

        // phase 3: read B[kk1] ni2,3; publish next tile (one vmcnt(0)/K-tile);
        // MFMA ni2,3
        b0 = *(const short8*)(bBase + pofs + (rB0 + 32 + l15) * 64 + sA1);
        b1 = *(const short8*)(bBase + pofs + (rB0 + 48 + l15) * 64 + sA1);
        if (pre) asm volatile("s_waitcnt vmcnt(0)" ::: "memory");
        RAW_BARRIER();
        __builtin_amdgcn_s_setprio(1);
#pragma unroll
        for (int mi = 0; mi < 8; mi++) {
            acc[mi][2] = __builtin_amdgcn_mfma_f32_16x16x32_bf16(af[mi], b0, acc[mi][2], 0, 0, 0);
            acc[mi][3] = __builtin_amdgcn_mfma_f32_16x16x32_bf16(af[mi], b1, acc[mi][3], 0, 0, 0);
        }
        __builtin_amdgcn_s_setprio(0);
    }
#undef STAGE_A
#undef STAGE_B
#undef RAW_BARRIER
}

// ---------------- QKV GEMM with fused RoPE + scatter ----------------
__global__ __launch_bounds__(512, 2) void gemm_qkv_rope(const u16* __restrict__ A,
                                                        const u16* __restrict__ BT,
                                                        const float* __restrict__ sinp,
                                                        const float* __restrict__ cosp,
                                                        u16* __restrict__ q_ws,
                                                        u16* __restrict__ k_ws,
                                                        u16* __restrict__ v_ws) {
    __shared__ u16 lds[65536];   // 128 KB
    int tid = threadIdx.x;
    int blk = blockIdx.x;
    int xcd = blk & 7, idx = blk >> 3;            // idx 0..95
    int rowBase = (xcd * 4 + (idx & 3)) * 256;    // rowTile 0..31 (4 per XCD)
    int colBase = (idx >> 2) * 256;               // colTile 0..23

    floatx4 acc[8][4];
#pragma unroll
    for (int mi = 0; mi < 8; mi++)
#pragma unroll
        for (int ni = 0; ni < 4; ni++) acc[mi][ni] = (floatx4){0.f, 0.f, 0.f, 0.f};

    gemm256_core(A, BT, rowBase, colBase, tid, lds, acc);

    int w = tid >> 6, lane = tid & 63, quad = lane >> 4, l15 = lane & 15;
    int wr = w >> 2, wc = w & 3;
    const float inv_sqrt_hd = 0.08838834764831845f;
#pragma unroll
    for (int mi = 0; mi < 8; mi++) {
#pragma unroll
        for (int ni = 0; ni < 4; ni++) {
            int j = colBase + wc * 64 + ni * 16 + l15;
            int sec = j >> 11;
            int jj = j & 2047;
            int h = jj >> 7, d = jj & 127;
            if (sec == 2) {
                // V: pack 4 consecutive-t bf16, transposed layout [b][h][d][t]
                int r0 = rowBase + wr * 128 + mi * 16 + quad * 4;
                int b = r0 >> 11, t0 = r0 & 2047;
                union { u16 s[4]; uint2 v; } pk;
#pragma unroll
                for (int reg = 0; reg < 4; reg++) pk.s[reg] = f2bf(acc[mi][ni][reg]);
                *(uint2*)(&v_ws[((size_t)(b * NH + h) * HD + d) * TSEQ + t0]) = pk.v;
            } else {
#pragma unroll
                for (int reg = 0; reg < 4; reg++) {
                    int r = rowBase + wr * 128 + mi * 16 + quad * 4 + reg;
                    int b = r >> 11, t = r & 2047;
                    float v = acc[mi][ni][reg];
                    float partner = __shfl_xor(v, 1, 64);
                    size_t dsti = (size_t)((b * NH + h) * TSEQ + t) * HD + d;
                    float s = sinp[t * HD + d], c = cosp[t * HD + d];
                    float o = v * c + ((d & 1) ? partner * s : -partner * s);
                    if (sec == 0) o *= inv_sqrt_hd;
                    ((sec == 0) ? q_ws : k_ws)[dsti] = f2bf(o);
                }
            }
        }
    }
}

// ---------------- projection GEMM ----------------
__global__ __launch_bounds__(512, 2) void gemm_proj(const u16* __restrict__ A,
                                                    const u16* __restrict__ BT,
                                                    float* __restrict__ out) {
    __shared__ u16 lds[65536];   // 128 KB
    int tid = threadIdx.x;
    int blk = blockIdx.x;
    int xcd = blk & 7, idx = blk >> 3;            // idx 0..31
    int rowBase = (xcd * 4 + (idx & 3)) * 256;    // rowTile 0..31
    int colBase = (idx >> 2) * 256;               // colTile 0..7

    floatx4 acc[8][4];
#pragma unroll
    for (int mi = 0; mi < 8; mi++)
#pragma unroll
        for (int ni = 0; ni < 4; ni++) acc[mi][ni] = (floatx4){0.f, 0.f, 0.f, 0.f};

    gemm256_core(A, BT, rowBase, colBase, tid, lds, acc);

    int w = tid >> 6, lane = tid & 63, quad = lane >> 4, l15 = lane & 15;
    int wr = w >> 2, wc = w & 3;
#pragma unroll
    for (int mi = 0; mi < 8; mi++) {
#pragma unroll
        for (int ni = 0; ni < 4; ni++) {
            int j = colBase + wc * 64 + ni * 16 + l15;
#pragma unroll
            for (int reg = 0; reg < 4; reg++) {
                int r = rowBase + wr * 128 + mi * 16 + quad * 4 + reg;
                out[(size_t)r * CM + j] = acc[mi][ni][reg];
            }
        }
    }
}

// ---------------- flash attention (causal, no-max softmax) ----------------
// 8 waves x 16 q-rows (512 threads). Latency-bound fix history: rounds 0-3
// showed dur invariant to traffic; the 8-wave restructure (round 4) dropped
// attn below the gemm rows. Staging fully coalesced; LDS XOR-swizzled;
// prefetch after second barrier.
// LDS: smem 32KB = Q stage, then Ks [16][64][8] + Vt [8][128][8]; Ps [128][72]
__global__ __launch_bounds__(512, 1) void attn_kernel(const u16* __restrict__ q_ws,
                                                      const u16* __restrict__ k_ws,
                                                      const u16* __restrict__ vt_ws,
                                                      u16* __restrict__ y_bf) {
    __shared__ u16 smem[16 * 1024];   // 32 KB
    __shared__ u16 Ps[128 * 72];      // 18.4 KB
    u16* Ks = smem;                   // [s=0..15][key^s7][8]
    u16* Vt = smem + 8192;            // [s=0..7][d^s][8]
    int tid = threadIdx.x;
    int w = tid >> 6, lane = tid & 63, quad = lane >> 4, l15 = lane & 15;
    int qt = 15 - (blockIdx.x >> 6);   // qt slow index: big tiles dispatch first
    int bh = blockIdx.x & 63;
    int b = bh >> 4, h = bh & 15;
    const u16* Qg = q_ws + (size_t)bh * TSEQ * HD;
    const u16* Kg = k_ws + (size_t)bh * TSEQ * HD;
    const u16* Vg = vt_ws + (size_t)bh * HD * TSEQ;

    // issue tile-0 K/V loads first (latency hides under Q staging below)
    uint4 kreg[2], vreg[2];
#pragma unroll
    for (int j = 0; j < 2; j++) {
        int idx = j * 512 + tid;
        int key = idx >> 4, s = idx & 15;
        kreg[j] = *(const uint4*)(Kg + (size_t)key * HD + s * 8);
    }
#pragma unroll
    for (int j = 0; j < 2; j++) {
        int idx = j * 512 + tid;
        int d = idx >> 3, s = idx & 7;
        vreg[j] = *(const uint4*)(Vg + (size_t)d * TSEQ + s * 8);
    }

    // stage Q tile (128x128) through smem, coalesced, then read fragments
#pragma unroll
    for (int j = 0; j < 4; j++) {
        int idx = j * 512 + tid;
        int row = idx >> 4, s = idx & 15;
        uint4 qv = *(const uint4*)(Qg + (size_t)(qt * 128 + row) * HD + s * 8);
        *(uint4*)(&smem[s * 1024 + ((row ^ (s & 7)) * 8)]) = qv;
    }
    __syncthreads();
    short8 qf[4];
#pragma unroll
    for (int kk = 0; kk < 4; kk++) {
        int row = w * 16 + l15;
        int s = kk * 4 + quad;
        qf[kk] = *(const short8*)(&smem[s * 1024 + ((row ^ (s & 7)) * 8)]);
    }
    // loop-top barrier protects smem reuse (Q -> Ks/Vt)

    floatx4 O[8];
#pragma unroll
    for (int f = 0; f < 8; f++) O[f] = (floatx4){0.f, 0.f, 0.f, 0.f};
    float l_i[4];
#pragma unroll
    for (int g = 0; g < 4; g++) l_i[g] = 0.f;

    int ktmax = 2 * qt + 1;
    for (int kt = 0; kt <= ktmax; kt++) {
        __syncthreads();
#pragma unroll
        for (int j = 0; j < 2; j++) {
            int idx = j * 512 + tid;
            int key = idx >> 4, s = idx & 15;
            *(uint4*)(&Ks[s * 512 + ((key ^ (s & 7)) * 8)]) = kreg[j];
        }
#pragma unroll
        for (int j = 0; j < 2; j++) {
            int idx = j * 512 + tid;
            int d = idx >> 3, s = idx & 7;
            *(uint4*)(&Vt[s * 1024 + ((d ^ s) * 8)]) = vreg[j];
        }
        __syncthreads();
        if (kt < ktmax) {   // prefetch next tile; overlaps compute below
            const u16* Ktg = Kg + (size_t)((kt + 1) * 64) * HD;
            const u16* Vtg = Vg + (kt + 1) * 64;
#pragma unroll
            for (int j = 0; j < 2; j++) {
                int idx = j * 512 + tid;
                int key = idx >> 4, s = idx & 15;
                kreg[j] = *(const uint4*)(Ktg + (size_t)key * HD + s * 8);
            }
#pragma unroll
            for (int j = 0; j < 2; j++) {
                int idx = j * 512 + tid;
                int d = idx >> 3, s = idx & 7;
                vreg[j] = *(const uint4*)(Vtg + (size_t)(d) * TSEQ + s * 8);
            }
        }

        // S = Q K^T : rows = this wave's 16 queries, cols = 64 keys
        floatx4 S[4];
#pragma unroll
        for (int nf = 0; nf < 4; nf++) {
            short8 bb[4];
#pragma unroll
            for (int kk = 0; kk < 4; kk++) {
                int s = kk * 4 + quad;
                int key = nf * 16 + l15;
                bb[kk] = *(const short8*)(&Ks[s * 512 + ((key ^ (s & 7)) * 8)]);
            }
            floatx4 a4 = (floatx4){0.f, 0.f, 0.f, 0.f};
#pragma unroll
            for (int kk = 0; kk < 4; kk++)
                a4 = __builtin_amdgcn_mfma_f32_16x16x32_bf16(qf[kk], bb[kk], a4, 0, 0, 0);
            S[nf] = a4;
        }
        if (kt >= 2 * qt) {   // diagonal region: mask key > query (exp(-1e4) == 0)
#pragma unroll
            for (int nf = 0; nf < 4; nf++) {
                int key = kt * 64 + nf * 16 + l15;
#pragma unroll
                for (int reg = 0; reg < 4; reg++) {
                    int query = qt * 128 + w * 16 + quad * 4 + reg;
                    if (key > query) S[nf][reg] = -1e4f;
                }
            }
        }
        // p = exp(S); accumulate per-lane l; stage P for the PV MFMA
#pragma unroll
        for (int nf = 0; nf < 4; nf++)
#pragma unroll
            for (int reg = 0; reg < 4; reg++) {
                float p = __expf(S[nf][reg]);
                l_i[reg] += p;
                Ps[(w * 16 + quad * 4 + reg) * 72 + nf * 16 + l15] = f2bf(p);
            }
        // O += P V  (Ps rows produced & consumed by same wave; no barrier needed)
        short8 pa[2];
#pragma unroll
        for (int kk = 0; kk < 2; kk++)
            pa[kk] = *(const short8*)(&Ps[(w * 16 + l15) * 72 + kk * 32 + quad * 8]);
#pragma unroll
        for (int f = 0; f < 8; f++) {
            short8 vb[2];
#pragma unroll
            for (int kk = 0; kk < 2; kk++) {
                int s = kk * 4 + quad;
                int d = f * 16 + l15;
                vb[kk] = *(const short8*)(&Vt[s * 1024 + ((d ^ s) * 8)]);
            }
#pragma unroll
            for (int kk = 0; kk < 2; kk++)
                O[f] = __builtin_amdgcn_mfma_f32_16x16x32_bf16(pa[kk], vb[kk], O[f], 0, 0, 0);
        }
    }

    float inv[4];
#pragma unroll
    for (int reg = 0; reg < 4; reg++) {
        float l = l_i[reg];
#pragma unroll
        for (int off = 1; off < 16; off <<= 1) l += __shfl_xor(l, off, 64);
        inv[reg] = 1.0f / l;
    }
#pragma unroll
    for (int f = 0; f < 8; f++)
#pragma unroll
        for (int reg = 0; reg < 4; reg++) {
            int t = qt * 128 + w * 16 + quad * 4 + reg;
            int col = h * HD + f * 16 + l15;
            y_bf[(size_t)(b * TSEQ + t) * CM + col] = f2bf(O[f][reg] * inv[reg]);
        }
}

extern "C" void kernel_launch(void* const* d_in, const int* in_sizes, int n_in,
                              void* d_out, int out_size, void* d_ws, size_t ws_size,
                              hipStream_t stream) {
    const float* x      = (const float*)d_in[0];
    const float* sinp   = (const float*)d_in[1];
    const float* cosp   = (const float*)d_in[2];
    const float* W_qkv  = (const float*)d_in[3];
    const float* W_proj = (const float*)d_in[4];
    float* out = (float*)d_out;

    char* ws = (char*)d_ws;
    size_t off = 0;
    u16* x_bf   = (u16*)(ws + off); off += (size_t)MROWS * CM * 2;   // 32 MB (reused as y)
    u16* wqkvT  = (u16*)(ws + off); off += (size_t)NQKV * CM * 2;    // 24 MB
    u16* wprojT = (u16*)(ws + off); off += (size_t)CM * CM * 2;      //  8 MB
    u16* q_ws   = (u16*)(ws + off); off += (size_t)MROWS * CM * 2;   // 32 MB
    u16* k_ws   = (u16*)(ws + off); off += (size_t)MROWS * CM * 2;   // 32 MB
    u16* v_ws   = (u16*)(ws + off); off += (size_t)MROWS * CM * 2;   // 32 MB ([b][h][d][t])
    u16* y_bf   = x_bf;   // x dead after qkv GEMM

    convert_x_kernel<<<(MROWS * CM) / (256 * 8), 256, 0, stream>>>(x, x_bf);
    transpose_bf_kernel<<<dim3(NQKV / 32, CM / 32), dim3(32, 8), 0, stream>>>(W_qkv, wqkvT, CM, NQKV);
    transpose_bf_kernel<<<dim3(CM / 32, CM / 32), dim3(32, 8), 0, stream>>>(W_proj, wprojT, CM, CM);
    gemm_qkv_rope<<<(MROWS / 256) * (NQKV / 256), 512, 0, stream>>>(x_bf, wqkvT, sinp, cosp,
                                                                    q_ws, k_ws, v_ws);
    attn_kernel<<<(TSEQ / 128) * 64, 512, 0, stream>>>(q_ws, k_ws, v_ws, y_bf);
    gemm_proj<<<(MROWS / 256) * (CM / 256), 512, 0, stream>>>(y_bf, wprojT, out);
}